// Round 1
// baseline (730.466 us; speedup 1.0000x reference)
//
#include <hip/hip_runtime.h>

// Problem constants (from reference)
#define NN 100000
#define NE 1600000

// ---------------- CSR build ----------------

__global__ void k_zero(int* __restrict__ p, int n) {
    int i = blockIdx.x * 256 + threadIdx.x;
    if (i < n) p[i] = 0;
}

__global__ void k_hist(const int* __restrict__ dst, int* __restrict__ deg, int E) {
    int e = blockIdx.x * 256 + threadIdx.x;
    if (e < E) atomicAdd(&deg[dst[e]], 1);
}

// dis[n] = rsqrt(in_deg + 1)  (self-loop adds 1; deg >= 1 always)
__global__ void k_dis_bsum(const int* __restrict__ deg, float* __restrict__ dis,
                           int* __restrict__ bsum, int N) {
    int t = threadIdx.x;
    int n = blockIdx.x * 256 + t;
    int d = (n < N) ? deg[n] : 0;
    if (n < N) dis[n] = rsqrtf((float)(d + 1));
    __shared__ int red[256];
    red[t] = d; __syncthreads();
    #pragma unroll
    for (int off = 128; off > 0; off >>= 1) {
        if (t < off) red[t] += red[t + off];
        __syncthreads();
    }
    if (t == 0) bsum[blockIdx.x] = red[0];
}

__global__ void k_scan512(const int* __restrict__ bsum, int* __restrict__ boff, int NB) {
    __shared__ int s[512];
    int t = threadIdx.x;
    int v = (t < NB) ? bsum[t] : 0;
    s[t] = v; __syncthreads();
    for (int off = 1; off < 512; off <<= 1) {
        int x = (t >= off) ? s[t - off] : 0;
        __syncthreads();
        s[t] += x;
        __syncthreads();
    }
    if (t < NB) boff[t] = s[t] - v;  // exclusive
}

__global__ void k_rowptr(const int* __restrict__ deg, const int* __restrict__ boff,
                         int* __restrict__ row_ptr, int* __restrict__ cnt, int N, int E) {
    int t = threadIdx.x;
    int n = blockIdx.x * 256 + t;
    int d = (n < N) ? deg[n] : 0;
    __shared__ int s[256];
    s[t] = d; __syncthreads();
    for (int off = 1; off < 256; off <<= 1) {
        int x = (t >= off) ? s[t - off] : 0;
        __syncthreads();
        s[t] += x;
        __syncthreads();
    }
    if (n < N) { row_ptr[n] = boff[blockIdx.x] + s[t] - d; cnt[n] = 0; }
    if (n == 0) row_ptr[N] = E;
}

__global__ void k_fill(const int* __restrict__ src, const int* __restrict__ dst,
                       const int* __restrict__ row_ptr, int* __restrict__ cnt,
                       int* __restrict__ col, int E) {
    int e = blockIdx.x * 256 + threadIdx.x;
    if (e < E) {
        int d = dst[e];
        int p = row_ptr[d] + atomicAdd(&cnt[d], 1);
        col[p] = src[e];
    }
}

// ---------------- feature pipeline ----------------

// xs = x * dis[row]  (float4 over N*64)
__global__ void k_scale(const float4* __restrict__ x4, const float* __restrict__ dis,
                        float4* __restrict__ xs4, int n4) {
    int i = blockIdx.x * 256 + threadIdx.x;
    if (i < n4) {
        int n = i >> 4;  // 16 float4 per node (64 floats)
        float s = dis[n];
        float4 v = x4[i];
        v.x *= s; v.y *= s; v.z *= s; v.w *= s;
        xs4[i] = v;
    }
}

// out[n] = dis[n] * (sum_{in-edges} g[src] + g[n]),  D=64, one wave per node
__global__ __launch_bounds__(256) void k_agg64(
    const float* __restrict__ g, const int* __restrict__ row_ptr,
    const int* __restrict__ col, const float* __restrict__ dis,
    float* __restrict__ out, int N) {
    int w = (blockIdx.x << 2) + (threadIdx.x >> 6);
    int lane = threadIdx.x & 63;
    if (w >= N) return;
    int b = row_ptr[w], e = row_ptr[w + 1];
    float acc = g[(w << 6) + lane];  // self-loop
    int i = b;
    for (; i + 4 <= e; i += 4) {
        int c0 = col[i], c1 = col[i + 1], c2 = col[i + 2], c3 = col[i + 3];
        float v0 = g[(c0 << 6) + lane], v1 = g[(c1 << 6) + lane];
        float v2 = g[(c2 << 6) + lane], v3 = g[(c3 << 6) + lane];
        acc += v0 + v1 + v2 + v3;
    }
    for (; i < e; i++) acc += g[(col[i] << 6) + lane];
    out[(w << 6) + lane] = dis[w] * acc;
}

// same, D=128 via float2 per lane (row = 512B coalesced)
__global__ __launch_bounds__(256) void k_agg128(
    const float* __restrict__ g, const int* __restrict__ row_ptr,
    const int* __restrict__ col, const float* __restrict__ dis,
    float* __restrict__ out, int N) {
    int w = (blockIdx.x << 2) + (threadIdx.x >> 6);
    int lane = threadIdx.x & 63;
    if (w >= N) return;
    const float2* g2 = (const float2*)g;
    float2* out2 = (float2*)out;
    int b = row_ptr[w], e = row_ptr[w + 1];
    float2 a = g2[(w << 6) + lane];
    float ax = a.x, ay = a.y;
    int i = b;
    for (; i + 4 <= e; i += 4) {
        int c0 = col[i], c1 = col[i + 1], c2 = col[i + 2], c3 = col[i + 3];
        float2 v0 = g2[(c0 << 6) + lane], v1 = g2[(c1 << 6) + lane];
        float2 v2 = g2[(c2 << 6) + lane], v3 = g2[(c3 << 6) + lane];
        ax += v0.x + v1.x + v2.x + v3.x;
        ay += v0.y + v1.y + v2.y + v3.y;
    }
    for (; i < e; i++) { float2 v = g2[(col[i] << 6) + lane]; ax += v.x; ay += v.y; }
    float s = dis[w];
    out2[(w << 6) + lane] = make_float2(s * ax, s * ay);
}

// dense: out = A[N,Din] @ W[Din,Dout]; optional (+bias, relu) then (*dis) epilogue
template <int Din, int Dout, bool BR, bool SCALE>
__global__ __launch_bounds__(256) void k_mm(
    const float* __restrict__ A, const float* __restrict__ W,
    const float* __restrict__ bias, const float* __restrict__ dis,
    float* __restrict__ out, int N) {
    constexpr int CG = Dout / 4;     // col groups (4 cols each)
    constexpr int NG = 256 / CG;     // node groups
    constexpr int NPT = 64 / NG;     // nodes per thread
    constexpr int STR = Din + 4;     // LDS row stride (16B-aligned, conflict-benign)
    constexpr int K4 = Din / 4;
    __shared__ float At[64 * STR];
    const int tid = threadIdx.x;
    const int n0 = blockIdx.x * 64;
    for (int idx = tid; idx < 64 * K4; idx += 256) {
        int node = idx / K4, k4 = idx % K4;
        int gn = n0 + node;
        float4 v = (gn < N) ? ((const float4*)A)[gn * K4 + k4]
                            : make_float4(0.f, 0.f, 0.f, 0.f);
        *(float4*)&At[node * STR + 4 * k4] = v;
    }
    __syncthreads();
    const int cg = tid % CG, ng = tid / CG, nb = ng * NPT;
    float acc[NPT][4];
    #pragma unroll
    for (int t = 0; t < NPT; t++) { acc[t][0] = acc[t][1] = acc[t][2] = acc[t][3] = 0.f; }
    const float4* W4 = (const float4*)W;
    for (int k = 0; k < Din; k += 4) {
        float4 w0 = W4[(k + 0) * CG + cg];
        float4 w1 = W4[(k + 1) * CG + cg];
        float4 w2 = W4[(k + 2) * CG + cg];
        float4 w3 = W4[(k + 3) * CG + cg];
        #pragma unroll
        for (int t = 0; t < NPT; t++) {
            float4 a = *(const float4*)&At[(nb + t) * STR + k];
            acc[t][0] += a.x * w0.x; acc[t][1] += a.x * w0.y; acc[t][2] += a.x * w0.z; acc[t][3] += a.x * w0.w;
            acc[t][0] += a.y * w1.x; acc[t][1] += a.y * w1.y; acc[t][2] += a.y * w1.z; acc[t][3] += a.y * w1.w;
            acc[t][0] += a.z * w2.x; acc[t][1] += a.z * w2.y; acc[t][2] += a.z * w2.z; acc[t][3] += a.z * w2.w;
            acc[t][0] += a.w * w3.x; acc[t][1] += a.w * w3.y; acc[t][2] += a.w * w3.z; acc[t][3] += a.w * w3.w;
        }
    }
    float4 b4 = BR ? ((const float4*)bias)[cg] : make_float4(0.f, 0.f, 0.f, 0.f);
    #pragma unroll
    for (int t = 0; t < NPT; t++) {
        int gn = n0 + nb + t;
        if (gn < N) {
            float4 r;
            r.x = acc[t][0] + b4.x; r.y = acc[t][1] + b4.y;
            r.z = acc[t][2] + b4.z; r.w = acc[t][3] + b4.w;
            if (BR) {
                r.x = fmaxf(r.x, 0.f); r.y = fmaxf(r.y, 0.f);
                r.z = fmaxf(r.z, 0.f); r.w = fmaxf(r.w, 0.f);
            }
            if (SCALE) { float s = dis[gn]; r.x *= s; r.y *= s; r.z *= s; r.w *= s; }
            ((float4*)out)[gn * CG + cg] = r;
        }
    }
}

// layer-3 aggregation fused with relu(+b3) and mean-pool partial reduction.
// h3 is never materialized. 1024 blocks x 4 waves, grid-stride over nodes.
__global__ __launch_bounds__(256) void k_aggpool(
    const float* __restrict__ g, const int* __restrict__ row_ptr,
    const int* __restrict__ col, const float* __restrict__ dis,
    const float* __restrict__ b3, float* __restrict__ partial, int N) {
    int lane = threadIdx.x & 63;
    int wib = threadIdx.x >> 6;                // wave in block, 0..3
    int gw = (blockIdx.x << 2) + wib;          // global wave id, 0..4095
    float bl = b3[lane];
    float accp = 0.f;
    for (int n = gw; n < N; n += 4096) {
        int b = row_ptr[n], e = row_ptr[n + 1];
        float s = g[(n << 6) + lane];
        int i = b;
        for (; i + 4 <= e; i += 4) {
            int c0 = col[i], c1 = col[i + 1], c2 = col[i + 2], c3 = col[i + 3];
            s += g[(c0 << 6) + lane] + g[(c1 << 6) + lane] +
                 g[(c2 << 6) + lane] + g[(c3 << 6) + lane];
        }
        for (; i < e; i++) s += g[(col[i] << 6) + lane];
        float v = dis[n] * s + bl;
        accp += fmaxf(v, 0.f);
    }
    __shared__ float red[4][64];
    red[wib][lane] = accp;
    __syncthreads();
    if (threadIdx.x < 64) {
        float r = red[0][threadIdx.x] + red[1][threadIdx.x] +
                  red[2][threadIdx.x] + red[3][threadIdx.x];
        partial[blockIdx.x * 64 + threadIdx.x] = r;
    }
}

// reduce partials -> mean pool -> fc(relu) -> fc -> softmax -> out[2]
__global__ __launch_bounds__(256) void k_head(
    const float* __restrict__ partial, const float* __restrict__ Wc1,
    const float* __restrict__ bc1, const float* __restrict__ Wc2,
    const float* __restrict__ bc2, float* __restrict__ out, int NB, float invN) {
    __shared__ float red[256];
    __shared__ float pooled[64];
    __shared__ float z[32];
    __shared__ float lg[2];
    int t = threadIdx.x;
    int lane = t & 63, grp = t >> 6;
    float s = 0.f;
    for (int b = grp; b < NB; b += 4) s += partial[b * 64 + lane];
    red[t] = s; __syncthreads();
    if (t < 64) pooled[t] = (red[t] + red[t + 64] + red[t + 128] + red[t + 192]) * invN;
    __syncthreads();
    if (t < 32) {
        float a = bc1[t];
        for (int l = 0; l < 64; l++) a += pooled[l] * Wc1[l * 32 + t];
        z[t] = fmaxf(a, 0.f);
    }
    __syncthreads();
    if (t < 2) {
        float a = bc2[t];
        for (int j = 0; j < 32; j++) a += z[j] * Wc2[j * 2 + t];
        lg[t] = a;
    }
    __syncthreads();
    if (t == 0) {
        float m = fmaxf(lg[0], lg[1]);
        float e0 = __expf(lg[0] - m), e1 = __expf(lg[1] - m);
        float inv = 1.f / (e0 + e1);
        out[0] = e0 * inv;
        out[1] = e1 * inv;
    }
}

// ---------------- launch ----------------

extern "C" void kernel_launch(void* const* d_in, const int* in_sizes, int n_in,
                              void* d_out, int out_size, void* d_ws, size_t ws_size,
                              hipStream_t stream) {
    (void)in_sizes; (void)n_in; (void)out_size; (void)ws_size;
    const int N = NN, E = NE;

    const float* x   = (const float*)d_in[0];
    const int*   ei  = (const int*)d_in[1];
    const int*   srcp = ei;
    const int*   dstp = ei + E;
    const float* W1 = (const float*)d_in[2];
    const float* b1 = (const float*)d_in[3];
    const float* W2 = (const float*)d_in[4];
    const float* b2 = (const float*)d_in[5];
    const float* W3 = (const float*)d_in[6];
    const float* b3 = (const float*)d_in[7];
    const float* Wc1 = (const float*)d_in[8];
    const float* bc1 = (const float*)d_in[9];
    const float* Wc2 = (const float*)d_in[10];
    const float* bc2 = (const float*)d_in[11];
    float* out = (float*)d_out;

    // workspace carve (256B aligned)
    char* base = (char*)d_ws;
    size_t off = 0;
    auto carve = [&](size_t bytes) -> char* {
        char* p = base + off;
        off = (off + bytes + 255) & ~(size_t)255;
        return p;
    };
    int*   deg     = (int*)carve((size_t)N * 4);
    int*   cnt     = (int*)carve((size_t)N * 4);
    int*   row_ptr = (int*)carve((size_t)(N + 1) * 4);
    int*   col     = (int*)carve((size_t)E * 4);
    int*   bsum    = (int*)carve(512 * 4);
    int*   boff    = (int*)carve(512 * 4);
    float* dis     = (float*)carve((size_t)N * 4);
    float* partial = (float*)carve((size_t)1024 * 64 * 4);
    float* bufA    = (float*)carve((size_t)N * 128 * 4);
    float* bufB    = (float*)carve((size_t)N * 128 * 4);

    const int NBN = (N + 255) / 256;   // 391
    const int NBE = (E + 255) / 256;   // 6250

    // CSR build (per-call; ws is re-poisoned each launch)
    k_zero<<<NBN, 256, 0, stream>>>(deg, N);
    k_hist<<<NBE, 256, 0, stream>>>(dstp, deg, E);
    k_dis_bsum<<<NBN, 256, 0, stream>>>(deg, dis, bsum, N);
    k_scan512<<<1, 512, 0, stream>>>(bsum, boff, NBN);
    k_rowptr<<<NBN, 256, 0, stream>>>(deg, boff, row_ptr, cnt, N, E);
    k_fill<<<NBE, 256, 0, stream>>>(srcp, dstp, row_ptr, cnt, col, E);

    // layer 1: aggregate x (64-dim) first, then transform 64->128
    k_scale<<<NBE, 256, 0, stream>>>((const float4*)x, dis, (float4*)bufA, N * 16);
    k_agg64<<<(N + 3) / 4, 256, 0, stream>>>(bufA, row_ptr, col, dis, bufB, N);
    k_mm<64, 128, true, true><<<(N + 63) / 64, 256, 0, stream>>>(bufB, W1, b1, dis, bufA, N);

    // layer 2: aggregate h1s (128), transform 128->128
    k_agg128<<<(N + 3) / 4, 256, 0, stream>>>(bufA, row_ptr, col, dis, bufB, N);
    k_mm<128, 128, true, true><<<(N + 63) / 64, 256, 0, stream>>>(bufB, W2, b2, dis, bufA, N);

    // layer 3: transform 128->64 first, then aggregate + relu(+b3) + pool (fused)
    k_mm<128, 64, false, false><<<(N + 63) / 64, 256, 0, stream>>>(bufA, W3, nullptr, nullptr, bufB, N);
    k_aggpool<<<1024, 256, 0, stream>>>(bufB, row_ptr, col, dis, b3, partial, N);

    // head MLP + softmax
    k_head<<<1, 256, 0, stream>>>(partial, Wc1, bc1, Wc2, bc2, out, 1024, 1.0f / (float)N);
}

// Round 2
// 678.344 us; speedup vs baseline: 1.0768x; 1.0768x over previous
//
#include <hip/hip_runtime.h>

// Problem constants (from reference)
#define NN 100000
#define NE 1600000

// ---------------- bf16 helpers (storage-only precision; math stays fp32) ----

__device__ __forceinline__ float b2f(unsigned short s) {
    unsigned int u = ((unsigned int)s) << 16;
    float f; __builtin_memcpy(&f, &u, 4); return f;
}
__device__ __forceinline__ unsigned short f2b(float f) {
    unsigned int u; __builtin_memcpy(&u, &f, 4);
    unsigned int r = (u + 0x7fffu + ((u >> 16) & 1u)) >> 16;  // RNE
    return (unsigned short)r;
}
__device__ __forceinline__ unsigned int pk2(float a, float b) {
    return (unsigned int)f2b(a) | ((unsigned int)f2b(b) << 16);
}
__device__ __forceinline__ float lo2f(unsigned int u) {
    unsigned int v = u << 16; float f; __builtin_memcpy(&f, &v, 4); return f;
}
__device__ __forceinline__ float hi2f(unsigned int u) {
    unsigned int v = u & 0xffff0000u; float f; __builtin_memcpy(&f, &v, 4); return f;
}

// ---------------- CSR build ----------------

__global__ void k_zero(int* __restrict__ p, int n) {
    int i = blockIdx.x * 256 + threadIdx.x;
    if (i < n) p[i] = 0;
}

__global__ void k_hist(const int* __restrict__ dst, int* __restrict__ deg, int E) {
    int e = blockIdx.x * 256 + threadIdx.x;
    if (e < E) atomicAdd(&deg[dst[e]], 1);
}

// dis[n] = rsqrt(in_deg + 1)  (self-loop adds 1)
__global__ void k_dis_bsum(const int* __restrict__ deg, float* __restrict__ dis,
                           int* __restrict__ bsum, int N) {
    int t = threadIdx.x;
    int n = blockIdx.x * 256 + t;
    int d = (n < N) ? deg[n] : 0;
    if (n < N) dis[n] = rsqrtf((float)(d + 1));
    __shared__ int red[256];
    red[t] = d; __syncthreads();
    #pragma unroll
    for (int off = 128; off > 0; off >>= 1) {
        if (t < off) red[t] += red[t + off];
        __syncthreads();
    }
    if (t == 0) bsum[blockIdx.x] = red[0];
}

__global__ void k_scan512(const int* __restrict__ bsum, int* __restrict__ boff, int NB) {
    __shared__ int s[512];
    int t = threadIdx.x;
    int v = (t < NB) ? bsum[t] : 0;
    s[t] = v; __syncthreads();
    for (int off = 1; off < 512; off <<= 1) {
        int x = (t >= off) ? s[t - off] : 0;
        __syncthreads();
        s[t] += x;
        __syncthreads();
    }
    if (t < NB) boff[t] = s[t] - v;  // exclusive
}

__global__ void k_rowptr(const int* __restrict__ deg, const int* __restrict__ boff,
                         int* __restrict__ row_ptr, int* __restrict__ cnt, int N, int E) {
    int t = threadIdx.x;
    int n = blockIdx.x * 256 + t;
    int d = (n < N) ? deg[n] : 0;
    __shared__ int s[256];
    s[t] = d; __syncthreads();
    for (int off = 1; off < 256; off <<= 1) {
        int x = (t >= off) ? s[t - off] : 0;
        __syncthreads();
        s[t] += x;
        __syncthreads();
    }
    if (n < N) { row_ptr[n] = boff[blockIdx.x] + s[t] - d; cnt[n] = 0; }
    if (n == 0) row_ptr[N] = E;
}

__global__ void k_fill(const int* __restrict__ src, const int* __restrict__ dst,
                       const int* __restrict__ row_ptr, int* __restrict__ cnt,
                       int* __restrict__ col, int E) {
    int e = blockIdx.x * 256 + threadIdx.x;
    if (e < E) {
        int d = dst[e];
        int p = row_ptr[d] + atomicAdd(&cnt[d], 1);
        col[p] = src[e];
    }
}

// ---------------- feature pipeline ----------------

// xb[n,f] = bf16(x[n,f] * dis[n])  (fuses the old k_scale; writes 12.8 MB)
__global__ void k_x2b(const float4* __restrict__ x4, const float* __restrict__ dis,
                      uint2* __restrict__ xb, int n4) {
    int i = blockIdx.x * 256 + threadIdx.x;
    if (i < n4) {
        int n = i >> 4;  // 16 float4 per node (64 floats)
        float s = dis[n];
        float4 v = x4[i];
        uint2 u;
        u.x = pk2(v.x * s, v.y * s);
        u.y = pk2(v.z * s, v.w * s);
        xb[i] = u;
    }
}

// out[n] = dis[n] * (sum_in g[src] + g[n]),  D=64 bf16 gather (128 B rows), fp32 out
__global__ __launch_bounds__(256) void k_agg64b(
    const unsigned short* __restrict__ g, const int* __restrict__ row_ptr,
    const int* __restrict__ col, const float* __restrict__ dis,
    float* __restrict__ out, int N) {
    int w = (blockIdx.x << 2) + (threadIdx.x >> 6);
    int lane = threadIdx.x & 63;
    if (w >= N) return;
    int b = row_ptr[w], e = row_ptr[w + 1];
    float acc = b2f(g[(w << 6) + lane]);  // self-loop
    int i = b;
    for (; i + 4 <= e; i += 4) {
        int c0 = col[i], c1 = col[i + 1], c2 = col[i + 2], c3 = col[i + 3];
        float v0 = b2f(g[(c0 << 6) + lane]), v1 = b2f(g[(c1 << 6) + lane]);
        float v2 = b2f(g[(c2 << 6) + lane]), v3 = b2f(g[(c3 << 6) + lane]);
        acc += v0 + v1 + v2 + v3;
    }
    for (; i < e; i++) acc += b2f(g[(col[i] << 6) + lane]);
    out[(w << 6) + lane] = dis[w] * acc;
}

// D=128 bf16 gather: lane loads one uint (2 bf16), row = 256 B. fp32 out.
__global__ __launch_bounds__(256) void k_agg128b(
    const unsigned int* __restrict__ g, const int* __restrict__ row_ptr,
    const int* __restrict__ col, const float* __restrict__ dis,
    float* __restrict__ out, int N) {
    int w = (blockIdx.x << 2) + (threadIdx.x >> 6);
    int lane = threadIdx.x & 63;
    if (w >= N) return;
    float2* out2 = (float2*)out;
    int b = row_ptr[w], e = row_ptr[w + 1];
    unsigned int a = g[(w << 6) + lane];
    float ax = lo2f(a), ay = hi2f(a);
    int i = b;
    for (; i + 4 <= e; i += 4) {
        int c0 = col[i], c1 = col[i + 1], c2 = col[i + 2], c3 = col[i + 3];
        unsigned int u0 = g[(c0 << 6) + lane], u1 = g[(c1 << 6) + lane];
        unsigned int u2 = g[(c2 << 6) + lane], u3 = g[(c3 << 6) + lane];
        ax += lo2f(u0) + lo2f(u1) + lo2f(u2) + lo2f(u3);
        ay += hi2f(u0) + hi2f(u1) + hi2f(u2) + hi2f(u3);
    }
    for (; i < e; i++) { unsigned int u = g[(col[i] << 6) + lane]; ax += lo2f(u); ay += hi2f(u); }
    float s = dis[w];
    out2[(w << 6) + lane] = make_float2(s * ax, s * ay);
}

// dense: out = A[N,Din] @ W[Din,Dout]; optional (+bias, relu), (*dis), bf16-out
template <int Din, int Dout, bool BR, bool SCALE, bool OUTB>
__global__ __launch_bounds__(256) void k_mm(
    const float* __restrict__ A, const float* __restrict__ W,
    const float* __restrict__ bias, const float* __restrict__ dis,
    float* __restrict__ out, int N) {
    constexpr int CG = Dout / 4;     // col groups (4 cols each)
    constexpr int NG = 256 / CG;     // node groups
    constexpr int NPT = 64 / NG;     // nodes per thread
    constexpr int STR = Din + 4;     // LDS row stride
    constexpr int K4 = Din / 4;
    __shared__ float At[64 * STR];
    const int tid = threadIdx.x;
    const int n0 = blockIdx.x * 64;
    for (int idx = tid; idx < 64 * K4; idx += 256) {
        int node = idx / K4, k4 = idx % K4;
        int gn = n0 + node;
        float4 v = (gn < N) ? ((const float4*)A)[gn * K4 + k4]
                            : make_float4(0.f, 0.f, 0.f, 0.f);
        *(float4*)&At[node * STR + 4 * k4] = v;
    }
    __syncthreads();
    const int cg = tid % CG, ng = tid / CG, nb = ng * NPT;
    float acc[NPT][4];
    #pragma unroll
    for (int t = 0; t < NPT; t++) { acc[t][0] = acc[t][1] = acc[t][2] = acc[t][3] = 0.f; }
    const float4* W4 = (const float4*)W;
    for (int k = 0; k < Din; k += 4) {
        float4 w0 = W4[(k + 0) * CG + cg];
        float4 w1 = W4[(k + 1) * CG + cg];
        float4 w2 = W4[(k + 2) * CG + cg];
        float4 w3 = W4[(k + 3) * CG + cg];
        #pragma unroll
        for (int t = 0; t < NPT; t++) {
            float4 a = *(const float4*)&At[(nb + t) * STR + k];
            acc[t][0] += a.x * w0.x; acc[t][1] += a.x * w0.y; acc[t][2] += a.x * w0.z; acc[t][3] += a.x * w0.w;
            acc[t][0] += a.y * w1.x; acc[t][1] += a.y * w1.y; acc[t][2] += a.y * w1.z; acc[t][3] += a.y * w1.w;
            acc[t][0] += a.z * w2.x; acc[t][1] += a.z * w2.y; acc[t][2] += a.z * w2.z; acc[t][3] += a.z * w2.w;
            acc[t][0] += a.w * w3.x; acc[t][1] += a.w * w3.y; acc[t][2] += a.w * w3.z; acc[t][3] += a.w * w3.w;
        }
    }
    float4 b4 = BR ? ((const float4*)bias)[cg] : make_float4(0.f, 0.f, 0.f, 0.f);
    #pragma unroll
    for (int t = 0; t < NPT; t++) {
        int gn = n0 + nb + t;
        if (gn < N) {
            float4 r;
            r.x = acc[t][0] + b4.x; r.y = acc[t][1] + b4.y;
            r.z = acc[t][2] + b4.z; r.w = acc[t][3] + b4.w;
            if (BR) {
                r.x = fmaxf(r.x, 0.f); r.y = fmaxf(r.y, 0.f);
                r.z = fmaxf(r.z, 0.f); r.w = fmaxf(r.w, 0.f);
            }
            if (SCALE) { float s = dis[gn]; r.x *= s; r.y *= s; r.z *= s; r.w *= s; }
            if (OUTB) {
                uint2 u; u.x = pk2(r.x, r.y); u.y = pk2(r.z, r.w);
                ((uint2*)out)[gn * CG + cg] = u;
            } else {
                ((float4*)out)[gn * CG + cg] = r;
            }
        }
    }
}

// layer-3 aggregation (bf16 gather, 128 B rows) fused with relu(+b3) + mean-pool
__global__ __launch_bounds__(256) void k_aggpool(
    const unsigned short* __restrict__ g, const int* __restrict__ row_ptr,
    const int* __restrict__ col, const float* __restrict__ dis,
    const float* __restrict__ b3, float* __restrict__ partial, int N) {
    int lane = threadIdx.x & 63;
    int wib = threadIdx.x >> 6;
    int gw = (blockIdx.x << 2) + wib;
    float bl = b3[lane];
    float accp = 0.f;
    for (int n = gw; n < N; n += 4096) {
        int b = row_ptr[n], e = row_ptr[n + 1];
        float s = b2f(g[(n << 6) + lane]);
        int i = b;
        for (; i + 4 <= e; i += 4) {
            int c0 = col[i], c1 = col[i + 1], c2 = col[i + 2], c3 = col[i + 3];
            s += b2f(g[(c0 << 6) + lane]) + b2f(g[(c1 << 6) + lane]) +
                 b2f(g[(c2 << 6) + lane]) + b2f(g[(c3 << 6) + lane]);
        }
        for (; i < e; i++) s += b2f(g[(col[i] << 6) + lane]);
        float v = dis[n] * s + bl;
        accp += fmaxf(v, 0.f);
    }
    __shared__ float red[4][64];
    red[wib][lane] = accp;
    __syncthreads();
    if (threadIdx.x < 64) {
        float r = red[0][threadIdx.x] + red[1][threadIdx.x] +
                  red[2][threadIdx.x] + red[3][threadIdx.x];
        partial[blockIdx.x * 64 + threadIdx.x] = r;
    }
}

// reduce partials -> mean pool -> fc(relu) -> fc -> softmax -> out[2]
__global__ __launch_bounds__(256) void k_head(
    const float* __restrict__ partial, const float* __restrict__ Wc1,
    const float* __restrict__ bc1, const float* __restrict__ Wc2,
    const float* __restrict__ bc2, float* __restrict__ out, int NB, float invN) {
    __shared__ float red[256];
    __shared__ float pooled[64];
    __shared__ float z[32];
    __shared__ float lg[2];
    int t = threadIdx.x;
    int lane = t & 63, grp = t >> 6;
    float s = 0.f;
    for (int b = grp; b < NB; b += 4) s += partial[b * 64 + lane];
    red[t] = s; __syncthreads();
    if (t < 64) pooled[t] = (red[t] + red[t + 64] + red[t + 128] + red[t + 192]) * invN;
    __syncthreads();
    if (t < 32) {
        float a = bc1[t];
        for (int l = 0; l < 64; l++) a += pooled[l] * Wc1[l * 32 + t];
        z[t] = fmaxf(a, 0.f);
    }
    __syncthreads();
    if (t < 2) {
        float a = bc2[t];
        for (int j = 0; j < 32; j++) a += z[j] * Wc2[j * 2 + t];
        lg[t] = a;
    }
    __syncthreads();
    if (t == 0) {
        float m = fmaxf(lg[0], lg[1]);
        float e0 = __expf(lg[0] - m), e1 = __expf(lg[1] - m);
        float inv = 1.f / (e0 + e1);
        out[0] = e0 * inv;
        out[1] = e1 * inv;
    }
}

// ---------------- launch ----------------

extern "C" void kernel_launch(void* const* d_in, const int* in_sizes, int n_in,
                              void* d_out, int out_size, void* d_ws, size_t ws_size,
                              hipStream_t stream) {
    (void)in_sizes; (void)n_in; (void)out_size; (void)ws_size;
    const int N = NN, E = NE;

    const float* x   = (const float*)d_in[0];
    const int*   ei  = (const int*)d_in[1];
    const int*   srcp = ei;
    const int*   dstp = ei + E;
    const float* W1 = (const float*)d_in[2];
    const float* b1 = (const float*)d_in[3];
    const float* W2 = (const float*)d_in[4];
    const float* b2 = (const float*)d_in[5];
    const float* W3 = (const float*)d_in[6];
    const float* b3 = (const float*)d_in[7];
    const float* Wc1 = (const float*)d_in[8];
    const float* bc1 = (const float*)d_in[9];
    const float* Wc2 = (const float*)d_in[10];
    const float* bc2 = (const float*)d_in[11];
    float* out = (float*)d_out;

    // workspace carve (256B aligned)
    char* base = (char*)d_ws;
    size_t off = 0;
    auto carve = [&](size_t bytes) -> char* {
        char* p = base + off;
        off = (off + bytes + 255) & ~(size_t)255;
        return p;
    };
    int*   deg     = (int*)carve((size_t)N * 4);
    int*   cnt     = (int*)carve((size_t)N * 4);
    int*   row_ptr = (int*)carve((size_t)(N + 1) * 4);
    int*   col     = (int*)carve((size_t)E * 4);
    int*   bsum    = (int*)carve(512 * 4);
    int*   boff    = (int*)carve(512 * 4);
    float* dis     = (float*)carve((size_t)N * 4);
    float* partial = (float*)carve((size_t)1024 * 64 * 4);
    // bf16 table region, time-shared: xb [N,64] -> h1b [N,128] -> g3b [N,64]
    char*  tbl     = carve((size_t)N * 128 * 2);
    float* bufA    = (float*)carve((size_t)N * 128 * 4);
    float* bufB    = (float*)carve((size_t)N * 128 * 4);

    unsigned short* xb  = (unsigned short*)tbl;  // bf16(x*dis), [N,64]
    unsigned short* h1b = (unsigned short*)tbl;  // bf16(h1s),   [N,128] (xb dead)
    unsigned short* g3b = (unsigned short*)tbl;  // bf16(g3),    [N,64]  (h1b dead)

    const int NBN = (N + 255) / 256;   // 391
    const int NBE = (E + 255) / 256;   // 6250

    // CSR build (per-call; ws is re-poisoned each launch)
    k_zero<<<NBN, 256, 0, stream>>>(deg, N);
    k_hist<<<NBE, 256, 0, stream>>>(dstp, deg, E);
    k_dis_bsum<<<NBN, 256, 0, stream>>>(deg, dis, bsum, N);
    k_scan512<<<1, 512, 0, stream>>>(bsum, boff, NBN);
    k_rowptr<<<NBN, 256, 0, stream>>>(deg, boff, row_ptr, cnt, N, E);
    k_fill<<<NBE, 256, 0, stream>>>(srcp, dstp, row_ptr, cnt, col, E);

    // layer 1: x -> bf16*dis table, aggregate (64-d), transform 64->128 (bf16 out)
    k_x2b<<<(N * 16 + 255) / 256, 256, 0, stream>>>((const float4*)x, dis, (uint2*)xb, N * 16);
    k_agg64b<<<(N + 3) / 4, 256, 0, stream>>>(xb, row_ptr, col, dis, bufB, N);
    k_mm<64, 128, true, true, true><<<(N + 63) / 64, 256, 0, stream>>>(bufB, W1, b1, dis, (float*)h1b, N);

    // layer 2: aggregate h1s (128-d bf16 gather), transform 128->128 (fp32 out)
    k_agg128b<<<(N + 3) / 4, 256, 0, stream>>>((const unsigned int*)h1b, row_ptr, col, dis, bufA, N);
    k_mm<128, 128, true, true, false><<<(N + 63) / 64, 256, 0, stream>>>(bufA, W2, b2, dis, bufB, N);

    // layer 3: transform 128->64 first (bf16 out), then aggregate+relu+pool (fused)
    k_mm<128, 64, false, false, true><<<(N + 63) / 64, 256, 0, stream>>>(bufB, W3, nullptr, nullptr, (float*)g3b, N);
    k_aggpool<<<1024, 256, 0, stream>>>(g3b, row_ptr, col, dis, b3, partial, N);

    // head MLP + softmax
    k_head<<<1, 256, 0, stream>>>(partial, Wc1, bc1, Wc2, bc2, out, 1024, 1.0f / (float)N);
}

// Round 3
// 526.683 us; speedup vs baseline: 1.3869x; 1.2880x over previous
//
#include <hip/hip_runtime.h>

// Problem constants (from reference)
#define NN 100000
#define NE 1600000
#define NBUCKET 391   // ceil(NN / 256)
#define CHUNK 4096    // edges per block in p2 scatter

// ---------------- bf16 helpers (storage-only precision; math stays fp32) ----

__device__ __forceinline__ float b2f(unsigned short s) {
    unsigned int u = ((unsigned int)s) << 16;
    float f; __builtin_memcpy(&f, &u, 4); return f;
}
__device__ __forceinline__ unsigned short f2b(float f) {
    unsigned int u; __builtin_memcpy(&u, &f, 4);
    unsigned int r = (u + 0x7fffu + ((u >> 16) & 1u)) >> 16;  // RNE
    return (unsigned short)r;
}
__device__ __forceinline__ unsigned int pk2(float a, float b) {
    return (unsigned int)f2b(a) | ((unsigned int)f2b(b) << 16);
}
__device__ __forceinline__ float lo2f(unsigned int u) {
    unsigned int v = u << 16; float f; __builtin_memcpy(&f, &v, 4); return f;
}
__device__ __forceinline__ float hi2f(unsigned int u) {
    unsigned int v = u & 0xffff0000u; float f; __builtin_memcpy(&f, &v, 4); return f;
}

// ---------------- CSR build via bucketed counting sort ----------------

__global__ void k_zero32(int* __restrict__ p, int n) {
    int i = blockIdx.x * 256 + threadIdx.x;
    if (i < n) p[i] = 0;
}

// phase 1: bucket counts (bucket = dst>>8), LDS histogram per block
__global__ __launch_bounds__(256) void k_p1(const int* __restrict__ dst,
                                            int* __restrict__ bcnt, int E) {
    __shared__ int h[NBUCKET];
    for (int i = threadIdx.x; i < NBUCKET; i += 256) h[i] = 0;
    __syncthreads();
    int stride = gridDim.x * 256;
    for (int i = blockIdx.x * 256 + threadIdx.x; i < E; i += stride)
        atomicAdd(&h[dst[i] >> 8], 1);
    __syncthreads();
    for (int i = threadIdx.x; i < NBUCKET; i += 256)
        if (h[i]) atomicAdd(&bcnt[i], h[i]);
}

// scan bucket counts -> bbase (exclusive, +total at end) and bfill (cursor copy)
__global__ void k_scanb(const int* __restrict__ bcnt, int* __restrict__ bbase,
                        int* __restrict__ bfill) {
    __shared__ int s[512];
    int t = threadIdx.x;
    int v = (t < NBUCKET) ? bcnt[t] : 0;
    s[t] = v; __syncthreads();
    for (int off = 1; off < 512; off <<= 1) {
        int x = (t >= off) ? s[t - off] : 0;
        __syncthreads();
        s[t] += x;
        __syncthreads();
    }
    if (t < NBUCKET) { int ex = s[t] - v; bbase[t] = ex; bfill[t] = ex; }
    if (t == NBUCKET) bbase[t] = s[511];   // = E
}

// phase 2: scatter packed (src | local<<17) entries into bucket-contiguous array
__global__ __launch_bounds__(256) void k_p2(const int* __restrict__ src,
                                            const int* __restrict__ dst,
                                            int* __restrict__ bfill,
                                            unsigned int* __restrict__ entries, int E) {
    __shared__ int h[NBUCKET];
    __shared__ int cur[NBUCKET];
    int c0 = blockIdx.x * CHUNK;
    int c1 = min(E, c0 + CHUNK);
    for (int i = threadIdx.x; i < NBUCKET; i += 256) h[i] = 0;
    __syncthreads();
    for (int i = c0 + threadIdx.x; i < c1; i += 256) atomicAdd(&h[dst[i] >> 8], 1);
    __syncthreads();
    for (int i = threadIdx.x; i < NBUCKET; i += 256)
        cur[i] = h[i] ? atomicAdd(&bfill[i], h[i]) : 0;
    __syncthreads();
    for (int i = c0 + threadIdx.x; i < c1; i += 256) {
        int d = dst[i];
        int bkt = d >> 8;
        int pos = atomicAdd(&cur[bkt], 1);
        entries[pos] = (unsigned int)src[i] | ((unsigned int)(d & 255) << 17);
    }
}

// phase 4: per-bucket histogram + scan -> row_ptr, dis, col (scatter is L2-local)
__global__ __launch_bounds__(256) void k_p4(const unsigned int* __restrict__ entries,
                                            const int* __restrict__ bbase,
                                            int* __restrict__ row_ptr,
                                            float* __restrict__ dis,
                                            int* __restrict__ col, int N) {
    __shared__ int cnt[256];
    __shared__ int cur[256];
    __shared__ int sc[256];
    int b = blockIdx.x;
    int e0 = bbase[b], e1 = bbase[b + 1];
    int t = threadIdx.x;
    cnt[t] = 0; __syncthreads();
    for (int i = e0 + t; i < e1; i += 256)
        atomicAdd(&cnt[(entries[i] >> 17) & 255], 1);
    __syncthreads();
    int v = cnt[t];
    sc[t] = v; __syncthreads();
    for (int off = 1; off < 256; off <<= 1) {
        int x = (t >= off) ? sc[t - off] : 0;
        __syncthreads();
        sc[t] += x;
        __syncthreads();
    }
    int ex = sc[t] - v;                       // exclusive scan
    int n = (b << 8) + t;
    if (n <= N) row_ptr[n] = e0 + ex;         // n==N lands at E in last bucket
    if (n < N) dis[n] = rsqrtf((float)(v + 1));
    cur[t] = e0 + ex;
    __syncthreads();
    for (int i = e0 + t; i < e1; i += 256) {
        unsigned int en = entries[i];
        int pos = atomicAdd(&cur[(en >> 17) & 255], 1);
        col[pos] = (int)(en & 0x1FFFF);
    }
}

// ---------------- feature pipeline ----------------

// xb[n,f] = bf16(x[n,f] * dis[n])
__global__ void k_x2b(const float4* __restrict__ x4, const float* __restrict__ dis,
                      uint2* __restrict__ xb, int n4) {
    int i = blockIdx.x * 256 + threadIdx.x;
    if (i < n4) {
        int n = i >> 4;
        float s = dis[n];
        float4 v = x4[i];
        uint2 u;
        u.x = pk2(v.x * s, v.y * s);
        u.y = pk2(v.z * s, v.w * s);
        xb[i] = u;
    }
}

// D=64 bf16 gather: 8 lanes x 16B per row -> 8 rows per wave-load.
// out[n] = dis[n] * (self + sum_in g[src]),  fp32 out [N,64]
__global__ __launch_bounds__(256) void k_agg64v(
    const unsigned short* __restrict__ g, const int* __restrict__ row_ptr,
    const int* __restrict__ col, const float* __restrict__ dis,
    float* __restrict__ out, int N) {
    int w = blockIdx.x * 4 + (threadIdx.x >> 6);
    if (w >= N) return;
    int lane = threadIdx.x & 63;
    int slot = lane >> 3, seg = lane & 7;
    const uint4* g4 = (const uint4*)g;
    int b = row_ptr[w], e = row_ptr[w + 1];
    int items = e - b + 1;                    // item 0 = self
    float a0=0,a1=0,a2=0,a3=0,a4=0,a5=0,a6=0,a7=0;
    for (int it = slot; it < items; it += 8) {
        int r = (it == 0) ? w : col[b + it - 1];
        uint4 u = g4[r * 8 + seg];
        a0 += lo2f(u.x); a1 += hi2f(u.x);
        a2 += lo2f(u.y); a3 += hi2f(u.y);
        a4 += lo2f(u.z); a5 += hi2f(u.z);
        a6 += lo2f(u.w); a7 += hi2f(u.w);
    }
    a0 += __shfl_xor(a0, 8); a0 += __shfl_xor(a0, 16); a0 += __shfl_xor(a0, 32);
    a1 += __shfl_xor(a1, 8); a1 += __shfl_xor(a1, 16); a1 += __shfl_xor(a1, 32);
    a2 += __shfl_xor(a2, 8); a2 += __shfl_xor(a2, 16); a2 += __shfl_xor(a2, 32);
    a3 += __shfl_xor(a3, 8); a3 += __shfl_xor(a3, 16); a3 += __shfl_xor(a3, 32);
    a4 += __shfl_xor(a4, 8); a4 += __shfl_xor(a4, 16); a4 += __shfl_xor(a4, 32);
    a5 += __shfl_xor(a5, 8); a5 += __shfl_xor(a5, 16); a5 += __shfl_xor(a5, 32);
    a6 += __shfl_xor(a6, 8); a6 += __shfl_xor(a6, 16); a6 += __shfl_xor(a6, 32);
    a7 += __shfl_xor(a7, 8); a7 += __shfl_xor(a7, 16); a7 += __shfl_xor(a7, 32);
    if (slot == 0) {
        float s = dis[w];
        float4* o = (float4*)(out + w * 64 + seg * 8);
        o[0] = make_float4(s*a0, s*a1, s*a2, s*a3);
        o[1] = make_float4(s*a4, s*a5, s*a6, s*a7);
    }
}

// D=128 bf16 gather: 16 lanes x 16B per row -> 4 rows per wave-load. fp32 out [N,128]
__global__ __launch_bounds__(256) void k_agg128v(
    const unsigned short* __restrict__ g, const int* __restrict__ row_ptr,
    const int* __restrict__ col, const float* __restrict__ dis,
    float* __restrict__ out, int N) {
    int w = blockIdx.x * 4 + (threadIdx.x >> 6);
    if (w >= N) return;
    int lane = threadIdx.x & 63;
    int slot = lane >> 4, seg = lane & 15;
    const uint4* g4 = (const uint4*)g;
    int b = row_ptr[w], e = row_ptr[w + 1];
    int items = e - b + 1;
    float a0=0,a1=0,a2=0,a3=0,a4=0,a5=0,a6=0,a7=0;
    for (int it = slot; it < items; it += 4) {
        int r = (it == 0) ? w : col[b + it - 1];
        uint4 u = g4[r * 16 + seg];
        a0 += lo2f(u.x); a1 += hi2f(u.x);
        a2 += lo2f(u.y); a3 += hi2f(u.y);
        a4 += lo2f(u.z); a5 += hi2f(u.z);
        a6 += lo2f(u.w); a7 += hi2f(u.w);
    }
    a0 += __shfl_xor(a0, 16); a0 += __shfl_xor(a0, 32);
    a1 += __shfl_xor(a1, 16); a1 += __shfl_xor(a1, 32);
    a2 += __shfl_xor(a2, 16); a2 += __shfl_xor(a2, 32);
    a3 += __shfl_xor(a3, 16); a3 += __shfl_xor(a3, 32);
    a4 += __shfl_xor(a4, 16); a4 += __shfl_xor(a4, 32);
    a5 += __shfl_xor(a5, 16); a5 += __shfl_xor(a5, 32);
    a6 += __shfl_xor(a6, 16); a6 += __shfl_xor(a6, 32);
    a7 += __shfl_xor(a7, 16); a7 += __shfl_xor(a7, 32);
    if (slot == 0) {
        float s = dis[w];
        float4* o = (float4*)(out + w * 128 + seg * 8);
        o[0] = make_float4(s*a0, s*a1, s*a2, s*a3);
        o[1] = make_float4(s*a4, s*a5, s*a6, s*a7);
    }
}

// dense: out = A[N,Din] @ W[Din,Dout]; optional (+bias, relu), (*dis), bf16-out
template <int Din, int Dout, bool BR, bool SCALE, bool OUTB>
__global__ __launch_bounds__(256) void k_mm(
    const float* __restrict__ A, const float* __restrict__ W,
    const float* __restrict__ bias, const float* __restrict__ dis,
    float* __restrict__ out, int N) {
    constexpr int CG = Dout / 4;
    constexpr int NG = 256 / CG;
    constexpr int NPT = 64 / NG;
    constexpr int STR = Din + 4;
    constexpr int K4 = Din / 4;
    __shared__ float At[64 * STR];
    const int tid = threadIdx.x;
    const int n0 = blockIdx.x * 64;
    for (int idx = tid; idx < 64 * K4; idx += 256) {
        int node = idx / K4, k4 = idx % K4;
        int gn = n0 + node;
        float4 v = (gn < N) ? ((const float4*)A)[gn * K4 + k4]
                            : make_float4(0.f, 0.f, 0.f, 0.f);
        *(float4*)&At[node * STR + 4 * k4] = v;
    }
    __syncthreads();
    const int cg = tid % CG, ng = tid / CG, nb = ng * NPT;
    float acc[NPT][4];
    #pragma unroll
    for (int t = 0; t < NPT; t++) { acc[t][0] = acc[t][1] = acc[t][2] = acc[t][3] = 0.f; }
    const float4* W4 = (const float4*)W;
    for (int k = 0; k < Din; k += 4) {
        float4 w0 = W4[(k + 0) * CG + cg];
        float4 w1 = W4[(k + 1) * CG + cg];
        float4 w2 = W4[(k + 2) * CG + cg];
        float4 w3 = W4[(k + 3) * CG + cg];
        #pragma unroll
        for (int t = 0; t < NPT; t++) {
            float4 a = *(const float4*)&At[(nb + t) * STR + k];
            acc[t][0] += a.x * w0.x; acc[t][1] += a.x * w0.y; acc[t][2] += a.x * w0.z; acc[t][3] += a.x * w0.w;
            acc[t][0] += a.y * w1.x; acc[t][1] += a.y * w1.y; acc[t][2] += a.y * w1.z; acc[t][3] += a.y * w1.w;
            acc[t][0] += a.z * w2.x; acc[t][1] += a.z * w2.y; acc[t][2] += a.z * w2.z; acc[t][3] += a.z * w2.w;
            acc[t][0] += a.w * w3.x; acc[t][1] += a.w * w3.y; acc[t][2] += a.w * w3.z; acc[t][3] += a.w * w3.w;
        }
    }
    float4 b4 = BR ? ((const float4*)bias)[cg] : make_float4(0.f, 0.f, 0.f, 0.f);
    #pragma unroll
    for (int t = 0; t < NPT; t++) {
        int gn = n0 + nb + t;
        if (gn < N) {
            float4 r;
            r.x = acc[t][0] + b4.x; r.y = acc[t][1] + b4.y;
            r.z = acc[t][2] + b4.z; r.w = acc[t][3] + b4.w;
            if (BR) {
                r.x = fmaxf(r.x, 0.f); r.y = fmaxf(r.y, 0.f);
                r.z = fmaxf(r.z, 0.f); r.w = fmaxf(r.w, 0.f);
            }
            if (SCALE) { float s = dis[gn]; r.x *= s; r.y *= s; r.z *= s; r.w *= s; }
            if (OUTB) {
                uint2 u; u.x = pk2(r.x, r.y); u.y = pk2(r.z, r.w);
                ((uint2*)out)[gn * CG + cg] = u;
            } else {
                ((float4*)out)[gn * CG + cg] = r;
            }
        }
    }
}

// layer-3: D=64 wide gather + relu(+b3) + mean-pool partial reduction (fused)
__global__ __launch_bounds__(256) void k_aggpoolv(
    const unsigned short* __restrict__ g, const int* __restrict__ row_ptr,
    const int* __restrict__ col, const float* __restrict__ dis,
    const float* __restrict__ b3, float* __restrict__ partial, int N) {
    int lane = threadIdx.x & 63, wib = threadIdx.x >> 6;
    int slot = lane >> 3, seg = lane & 7;
    const uint4* g4 = (const uint4*)g;
    float bl[8];
    #pragma unroll
    for (int j = 0; j < 8; j++) bl[j] = b3[seg * 8 + j];
    float ap[8] = {0,0,0,0,0,0,0,0};
    int gw = blockIdx.x * 4 + wib;
    for (int n = gw; n < N; n += 4096) {
        int b = row_ptr[n], e = row_ptr[n + 1];
        int items = e - b + 1;
        float a[8] = {0,0,0,0,0,0,0,0};
        for (int it = slot; it < items; it += 8) {
            int r = (it == 0) ? n : col[b + it - 1];
            uint4 u = g4[r * 8 + seg];
            a[0] += lo2f(u.x); a[1] += hi2f(u.x);
            a[2] += lo2f(u.y); a[3] += hi2f(u.y);
            a[4] += lo2f(u.z); a[5] += hi2f(u.z);
            a[6] += lo2f(u.w); a[7] += hi2f(u.w);
        }
        #pragma unroll
        for (int j = 0; j < 8; j++) {
            a[j] += __shfl_xor(a[j], 8);
            a[j] += __shfl_xor(a[j], 16);
            a[j] += __shfl_xor(a[j], 32);
        }
        if (slot == 0) {
            float s = dis[n];
            #pragma unroll
            for (int j = 0; j < 8; j++) ap[j] += fmaxf(s * a[j] + bl[j], 0.f);
        }
    }
    __shared__ float red[4][64];
    if (slot == 0) {
        #pragma unroll
        for (int j = 0; j < 8; j++) red[wib][seg * 8 + j] = ap[j];
    }
    __syncthreads();
    int t = threadIdx.x;
    if (t < 64) {
        float r = red[0][t] + red[1][t] + red[2][t] + red[3][t];
        partial[blockIdx.x * 64 + t] = r;
    }
}

// reduce partials -> mean pool -> fc(relu) -> fc -> softmax -> out[2]
__global__ __launch_bounds__(256) void k_head(
    const float* __restrict__ partial, const float* __restrict__ Wc1,
    const float* __restrict__ bc1, const float* __restrict__ Wc2,
    const float* __restrict__ bc2, float* __restrict__ out, int NB, float invN) {
    __shared__ float red[256];
    __shared__ float pooled[64];
    __shared__ float z[32];
    __shared__ float lg[2];
    int t = threadIdx.x;
    int lane = t & 63, grp = t >> 6;
    float s = 0.f;
    for (int b = grp; b < NB; b += 4) s += partial[b * 64 + lane];
    red[t] = s; __syncthreads();
    if (t < 64) pooled[t] = (red[t] + red[t + 64] + red[t + 128] + red[t + 192]) * invN;
    __syncthreads();
    if (t < 32) {
        float a = bc1[t];
        for (int l = 0; l < 64; l++) a += pooled[l] * Wc1[l * 32 + t];
        z[t] = fmaxf(a, 0.f);
    }
    __syncthreads();
    if (t < 2) {
        float a = bc2[t];
        for (int j = 0; j < 32; j++) a += z[j] * Wc2[j * 2 + t];
        lg[t] = a;
    }
    __syncthreads();
    if (t == 0) {
        float m = fmaxf(lg[0], lg[1]);
        float e0 = __expf(lg[0] - m), e1 = __expf(lg[1] - m);
        float inv = 1.f / (e0 + e1);
        out[0] = e0 * inv;
        out[1] = e1 * inv;
    }
}

// ---------------- launch ----------------

extern "C" void kernel_launch(void* const* d_in, const int* in_sizes, int n_in,
                              void* d_out, int out_size, void* d_ws, size_t ws_size,
                              hipStream_t stream) {
    (void)in_sizes; (void)n_in; (void)out_size; (void)ws_size;
    const int N = NN, E = NE;

    const float* x   = (const float*)d_in[0];
    const int*   ei  = (const int*)d_in[1];
    const int*   srcp = ei;
    const int*   dstp = ei + E;
    const float* W1 = (const float*)d_in[2];
    const float* b1 = (const float*)d_in[3];
    const float* W2 = (const float*)d_in[4];
    const float* b2 = (const float*)d_in[5];
    const float* W3 = (const float*)d_in[6];
    const float* b3 = (const float*)d_in[7];
    const float* Wc1 = (const float*)d_in[8];
    const float* bc1 = (const float*)d_in[9];
    const float* Wc2 = (const float*)d_in[10];
    const float* bc2 = (const float*)d_in[11];
    float* out = (float*)d_out;

    // workspace carve (256B aligned)
    char* base = (char*)d_ws;
    size_t off = 0;
    auto carve = [&](size_t bytes) -> char* {
        char* p = base + off;
        off = (off + bytes + 255) & ~(size_t)255;
        return p;
    };
    int*   bcnt    = (int*)carve((size_t)NBUCKET * 4);
    int*   bbase   = (int*)carve((size_t)(NBUCKET + 1) * 4);
    int*   bfill   = (int*)carve((size_t)NBUCKET * 4);
    int*   row_ptr = (int*)carve((size_t)(N + 1) * 4);
    int*   col     = (int*)carve((size_t)E * 4);
    float* dis     = (float*)carve((size_t)N * 4);
    float* partial = (float*)carve((size_t)1024 * 64 * 4);
    // bf16 table region, time-shared: entries -> xb -> h1b -> g3b
    char*  tbl     = carve((size_t)N * 128 * 2);
    float* bufA    = (float*)carve((size_t)N * 128 * 4);
    float* bufB    = (float*)carve((size_t)N * 128 * 4);

    unsigned int*   entries = (unsigned int*)tbl;   // [E] packed, dead after p4
    unsigned short* xb  = (unsigned short*)tbl;     // bf16(x*dis), [N,64]
    unsigned short* h1b = (unsigned short*)tbl;     // bf16(h1s),   [N,128]
    unsigned short* g3b = (unsigned short*)tbl;     // bf16(g3),    [N,64]

    // ---- CSR build (bucketed counting sort) ----
    k_zero32<<<(NBUCKET + 255) / 256, 256, 0, stream>>>(bcnt, NBUCKET);
    k_p1<<<512, 256, 0, stream>>>(dstp, bcnt, E);
    k_scanb<<<1, 512, 0, stream>>>(bcnt, bbase, bfill);
    k_p2<<<(E + CHUNK - 1) / CHUNK, 256, 0, stream>>>(srcp, dstp, bfill, entries, E);
    k_p4<<<NBUCKET, 256, 0, stream>>>(entries, bbase, row_ptr, dis, col, N);

    // ---- layer 1: x -> bf16*dis table, aggregate (64-d), transform 64->128 ----
    k_x2b<<<(N * 16 + 255) / 256, 256, 0, stream>>>((const float4*)x, dis, (uint2*)xb, N * 16);
    k_agg64v<<<(N + 3) / 4, 256, 0, stream>>>(xb, row_ptr, col, dis, bufB, N);
    k_mm<64, 128, true, true, true><<<(N + 63) / 64, 256, 0, stream>>>(bufB, W1, b1, dis, (float*)h1b, N);

    // ---- layer 2: aggregate h1s (128-d), transform 128->128 ----
    k_agg128v<<<(N + 3) / 4, 256, 0, stream>>>(h1b, row_ptr, col, dis, bufA, N);
    k_mm<128, 128, true, true, false><<<(N + 63) / 64, 256, 0, stream>>>(bufA, W2, b2, dis, bufB, N);

    // ---- layer 3: transform 128->64 first, then aggregate+relu+pool (fused) ----
    k_mm<128, 64, false, false, true><<<(N + 63) / 64, 256, 0, stream>>>(bufB, W3, nullptr, nullptr, (float*)g3b, N);
    k_aggpoolv<<<1024, 256, 0, stream>>>(g3b, row_ptr, col, dis, b3, partial, N);

    // ---- head MLP + softmax ----
    k_head<<<1, 256, 0, stream>>>(partial, Wc1, bc1, Wc2, bc2, out, 1024, 1.0f / (float)N);
}